// Round 6
// baseline (70.594 us; speedup 1.0000x reference)
//
#include <hip/hip_runtime.h>
#include <cstdint>

#pragma clang fp contract(off)

typedef float v2f __attribute__((ext_vector_type(2)));

#define P_N 2048
#define F_N 8192
#define TPB 256
#define FPT 32            // faces per tile
#define NT (F_N / FPT)    // 256 tiles

// ---------------- workspace layout (new path) ----------------
// [0, 16384)            : best keys, u64 x 2048
// [16384, 24576)        : min_ub, u32(float bits) x 2048
// [24576, 24576+33.5MB) : LB pairs, u32 x (F_N/2 x P_N)  (2 x bf16 per word)
#define WS_BEST_OFF   0
#define WS_MINUB_OFF  16384
#define WS_LB_OFF     24576
#define WS_NEEDED     (24576ull + (unsigned long long)(F_N / 2) * P_N * 4ull)

// =================== shared exact helpers (proven R1-R5) ===================

// 21 per-face constants, matching reference rounding exactly.
__device__ __forceinline__ void face_setup(
    const float* __restrict__ vertices, const int* __restrict__ faces, int f,
    float* fd)
{
#pragma clang fp contract(off)
    int i0 = faces[3 * f + 0];
    int i1 = faces[3 * f + 1];
    int i2 = faces[3 * f + 2];
    float ax = vertices[3 * i0 + 0], ay = vertices[3 * i0 + 1], az = vertices[3 * i0 + 2];
    float bx = vertices[3 * i1 + 0], by = vertices[3 * i1 + 1], bz = vertices[3 * i1 + 2];
    float cx = vertices[3 * i2 + 0], cy = vertices[3 * i2 + 1], cz = vertices[3 * i2 + 2];
    float abx = bx - ax, aby = by - ay, abz = bz - az;
    float acx = cx - ax, acy = cy - ay, acz = cz - az;
    float daab = (ax * abx + ay * aby) + az * abz;
    float daac = (ax * acx + ay * acy) + az * acz;
    float dbab = (bx * abx + by * aby) + bz * abz;
    float dbac = (bx * acx + by * acy) + bz * acz;
    float dcab = (cx * abx + cy * aby) + cz * abz;
    float dcac = (cx * acx + cy * acy) + cz * acz;
    fd[0] = ax;  fd[1] = ay;  fd[2] = az;
    fd[3] = bx;  fd[4] = by;  fd[5] = bz;
    fd[6] = cx;  fd[7] = cy;  fd[8] = cz;
    fd[9] = abx; fd[10] = aby; fd[11] = abz;
    fd[12] = acx; fd[13] = acy; fd[14] = acz;
    fd[15] = daab; fd[16] = daac; fd[17] = dbab;
    fd[18] = dbac; fd[19] = dcab; fd[20] = dcac;
}

// Bit-identical to reference where-chain (5 IEEE divides).
__device__ __forceinline__ void tri_eval_exact(
    float px, float py, float pz,
    const float* fd,
    float& w1o, float& w2o, float& w3o, float& disto)
{
#pragma clang fp contract(off)
    const float ax = fd[0], ay = fd[1], az = fd[2];
    const float bx = fd[3], by = fd[4], bz = fd[5];
    const float cx = fd[6], cy = fd[7], cz = fd[8];
    const float abx = fd[9], aby = fd[10], abz = fd[11];
    const float acx = fd[12], acy = fd[13], acz = fd[14];
    const float daab = fd[15], daac = fd[16], dbab = fd[17];
    const float dbac = fd[18], dcab = fd[19], dcac = fd[20];

    float pab = fmaf(pz, abz, fmaf(py, aby, px * abx));
    float pac = fmaf(pz, acz, fmaf(py, acy, px * acx));

    float d1 = pab - daab;
    float d2 = pac - daac;
    float d3 = pab - dbab;
    float d4 = pac - dbac;
    float d5 = pab - dcab;
    float d6 = pac - dcac;

    float vc = d1 * d4 - d3 * d2;
    float vb = d5 * d2 - d1 * d6;
    float va = d3 * d6 - d5 * d4;

    float denom = (va + vb) + vc;
    float dn = (denom == 0.0f) ? 1.0f : denom;
    float v7 = vb / dn;
    float w7 = vc / dn;
    float w1 = (1.0f - v7) - w7;
    float w2 = v7;
    float w3 = w7;

    float e63 = d4 - d3;
    float e65 = d5 - d6;
    float t6d = e63 + e65; t6d = (t6d == 0.0f) ? 1.0f : t6d;
    float t6 = e63 / t6d;
    if ((va <= 0.0f) & (e63 >= 0.0f) & (e65 >= 0.0f)) { w1 = 0.0f; w2 = 1.0f - t6; w3 = t6; }

    float t5d = d2 - d6; t5d = (t5d == 0.0f) ? 1.0f : t5d;
    float t5 = d2 / t5d;
    if ((vb <= 0.0f) & (d2 >= 0.0f) & (d6 <= 0.0f)) { w1 = 1.0f - t5; w2 = 0.0f; w3 = t5; }

    if ((d6 >= 0.0f) & (d5 <= d6)) { w1 = 0.0f; w2 = 0.0f; w3 = 1.0f; }

    float t3d = d1 - d3; t3d = (t3d == 0.0f) ? 1.0f : t3d;
    float t3 = d1 / t3d;
    if ((vc <= 0.0f) & (d1 >= 0.0f) & (d3 <= 0.0f)) { w1 = 1.0f - t3; w2 = t3; w3 = 0.0f; }

    if ((d3 >= 0.0f) & (d4 <= d3)) { w1 = 0.0f; w2 = 1.0f; w3 = 0.0f; }

    if ((d1 <= 0.0f) & (d2 <= 0.0f)) { w1 = 1.0f; w2 = 0.0f; w3 = 0.0f; }

    float cpx = (w1 * ax + w2 * bx) + w3 * cx;
    float cpy = (w1 * ay + w2 * by) + w3 * cy;
    float cpz = (w1 * az + w2 * bz) + w3 * cz;
    float dx = px - cpx, dy = py - cpy, dz = pz - cpz;
    float dist = (dx * dx + dy * dy) + dz * dz;

    w1o = w1; w2o = w2; w3o = w3; disto = dist;
}

// =================== phase 1: screening bounds ===================

#define NARR 35
enum {
    iAX = 0, iAY, iAZ,
    iABX, iABY, iABZ,
    iACX, iACY, iACZ,
    iA, iB, iC, iD, iE, iF,
    iKCS, iKCT, iKCC,       // vc ~ kcs*s + kct*t + kcc
    iKBS, iKBT, iKBC,       // vb
    iKAS, iKAT, iKAC,       // va
    iNX, iNY, iNZ, iMND,    // normal; -(n . a)
    iIAB, iIAC, iIBC, iINN, // guarded reciprocals of |ab|^2,|ac|^2,|bc|^2,|n|^2
    iABAB, iACAC,
    iMARG
};

__device__ __forceinline__ void stage_screen(
    const float* __restrict__ v, const int* __restrict__ fc, int f, int slot,
    float sq[NARR][FPT])
{
#pragma clang fp contract(off)
    int i0 = fc[3 * f + 0], i1 = fc[3 * f + 1], i2 = fc[3 * f + 2];
    float ax = v[3 * i0], ay = v[3 * i0 + 1], az = v[3 * i0 + 2];
    float bx = v[3 * i1], by = v[3 * i1 + 1], bz = v[3 * i1 + 2];
    float cx = v[3 * i2], cy = v[3 * i2 + 1], cz = v[3 * i2 + 2];
    float abx = bx - ax, aby = by - ay, abz = bz - az;
    float acx = cx - ax, acy = cy - ay, acz = cz - az;
    float A = (ax * abx + ay * aby) + az * abz;
    float B = (ax * acx + ay * acy) + az * acz;
    float C = (bx * abx + by * aby) + bz * abz;
    float D = (bx * acx + by * acy) + bz * acz;
    float E = (cx * abx + cy * aby) + cz * abz;
    float F = (cx * acx + cy * acy) + cz * acz;
    // vc=d1d4-d3d2, vb=d5d2-d1d6, va=d3d6-d5d4 are linear in s=p.ab, t=p.ac
    float kcs = B - D, kct = C - A, kcc = A * D - C * B;
    float kbs = F - B, kbt = A - E, kbc = E * B - A * F;
    float kas = D - F, kat = E - C, kac = C * F - E * D;
    float nx = aby * acz - abz * acy;
    float ny = abz * acx - abx * acz;
    float nz = abx * acy - aby * acx;
    float nn = (nx * nx + ny * ny) + nz * nz;
    float abab = (abx * abx + aby * aby) + abz * abz;
    float acac = (acx * acx + acy * acy) + acz * acz;
    float bcx = cx - bx, bcy = cy - by, bcz = cz - bz;
    float bcbc = (bcx * bcx + bcy * bcy) + bcz * bcz;
    float inv_ab = abab > 0.0f ? 1.0f / abab : 0.0f;
    float inv_ac = acac > 0.0f ? 1.0f / acac : 0.0f;
    float inv_bc = bcbc > 0.0f ? 1.0f / bcbc : 0.0f;
    float inv_nn = nn >= 1e-2f ? 1.0f / nn : 0.0f;
    float L2 = abab + acac;
    float infl = 1e-4f * L2 * sqrtf(L2) * inv_nn;  // ~ rounding inflation of interior cp
    float marg = 3e-4f + infl * infl;
    bool bad = (nn < 1e-2f) | (abab < 1e-3f) | (acac < 1e-3f) | (bcbc < 1e-3f) | (marg > 0.25f);
    if (bad) marg = 1e30f;  // flag: LB=0 (always candidate), UB=|pa|^2
    float mnda = -((nx * ax + ny * ay) + nz * az);

    sq[iAX][slot] = ax;  sq[iAY][slot] = ay;  sq[iAZ][slot] = az;
    sq[iABX][slot] = abx; sq[iABY][slot] = aby; sq[iABZ][slot] = abz;
    sq[iACX][slot] = acx; sq[iACY][slot] = acy; sq[iACZ][slot] = acz;
    sq[iA][slot] = A; sq[iB][slot] = B; sq[iC][slot] = C;
    sq[iD][slot] = D; sq[iE][slot] = E; sq[iF][slot] = F;
    sq[iKCS][slot] = kcs; sq[iKCT][slot] = kct; sq[iKCC][slot] = kcc;
    sq[iKBS][slot] = kbs; sq[iKBT][slot] = kbt; sq[iKBC][slot] = kbc;
    sq[iKAS][slot] = kas; sq[iKAT][slot] = kat; sq[iKAC][slot] = kac;
    sq[iNX][slot] = nx; sq[iNY][slot] = ny; sq[iNZ][slot] = nz; sq[iMND][slot] = mnda;
    sq[iIAB][slot] = inv_ab; sq[iIAC][slot] = inv_ac; sq[iIBC][slot] = inv_bc; sq[iINN][slot] = inv_nn;
    sq[iABAB][slot] = abab; sq[iACAC][slot] = acac;
    sq[iMARG][slot] = marg;
}

__device__ __forceinline__ void screen_face(
    float d1, float d2, float d3, float d4, float d5, float d6,
    float va, float vb, float vc, float e63, float e65,
    float pa2, float pb2, float pc2,
    float sub3, float sub5, float sub6, float subI,
    float marg,
    float& ubmin, unsigned& lb16)
{
    bool m1 = (d1 <= 0.0f) & (d2 <= 0.0f);
    bool m2 = (d3 >= 0.0f) & (d4 <= d3);
    bool m3 = (vc <= 0.0f) & (d1 >= 0.0f) & (d3 <= 0.0f);
    bool m4 = (d6 >= 0.0f) & (d5 <= d6);
    bool m5 = (vb <= 0.0f) & (d2 >= 0.0f) & (d6 <= 0.0f);
    bool m6 = (va <= 0.0f) & (e63 >= 0.0f) & (e65 >= 0.0f);
    float screen = m1 ? pa2 : m2 ? pb2 : m3 ? sub3 : m4 ? pc2 : m5 ? sub5 : m6 ? sub6 : subI;
    screen = fmaxf(screen, 0.0f);
    bool bad = marg > 0.25f;
    float ub = bad ? (pa2 + 3e-4f) : (screen + marg);
    ubmin = fminf(ubmin, ub);
    float lb = fmaxf(fmaf(0.99f, screen, -marg), 0.0f);  // rel+abs margin, >=0
    lb16 = __float_as_uint(lb) >> 16;                    // bf16 truncate = round-down
}

__global__ __launch_bounds__(TPB) void k_screen(
    const float* __restrict__ points,
    const float* __restrict__ vertices,
    const int* __restrict__ faces,
    unsigned* __restrict__ minub,
    unsigned* __restrict__ lbout)
{
#pragma clang fp contract(off)
    __shared__ float sq[NARR][FPT];

    const int pblk = blockIdx.x;  // 0..7
    const int fblk = blockIdx.y;  // 0..255
    const int t = threadIdx.x;

    if (t < FPT) stage_screen(vertices, faces, fblk * FPT + t, t, sq);
    __syncthreads();

    const int p = pblk * TPB + t;
    const float px = points[3 * p + 0];
    const float py = points[3 * p + 1];
    const float pz = points[3 * p + 2];
    const v2f pxv = {px, px}, pyv = {py, py}, pzv = {pz, pz};
    const v2f n2v = {-2.0f, -2.0f};

    float ubmin = 3e38f;

#pragma unroll 2
    for (int jp = 0; jp < FPT / 2; ++jp) {
        const int j = jp * 2;
#define L2D(k) (*(const v2f*)&sq[k][j])
        v2f s = __builtin_elementwise_fma(pzv, L2D(iABZ),
                    __builtin_elementwise_fma(pyv, L2D(iABY), pxv * L2D(iABX)));
        v2f tt = __builtin_elementwise_fma(pzv, L2D(iACZ),
                    __builtin_elementwise_fma(pyv, L2D(iACY), pxv * L2D(iACX)));

        v2f d1 = s - L2D(iA);
        v2f d2 = tt - L2D(iB);
        v2f d3 = s - L2D(iC);
        v2f d4 = tt - L2D(iD);
        v2f d5 = s - L2D(iE);
        v2f d6 = tt - L2D(iF);

        v2f vc = __builtin_elementwise_fma(s, L2D(iKCS),
                    __builtin_elementwise_fma(tt, L2D(iKCT), L2D(iKCC)));
        v2f vb = __builtin_elementwise_fma(s, L2D(iKBS),
                    __builtin_elementwise_fma(tt, L2D(iKBT), L2D(iKBC)));
        v2f va = __builtin_elementwise_fma(s, L2D(iKAS),
                    __builtin_elementwise_fma(tt, L2D(iKAT), L2D(iKAC)));

        v2f e63 = d4 - d3;
        v2f e65 = d5 - d6;

        v2f nd = __builtin_elementwise_fma(L2D(iNZ), pzv,
                    __builtin_elementwise_fma(L2D(iNY), pyv,
                        __builtin_elementwise_fma(L2D(iNX), pxv, L2D(iMND))));

        v2f dax = pxv - L2D(iAX);
        v2f day = pyv - L2D(iAY);
        v2f daz = pzv - L2D(iAZ);
        v2f pa2 = __builtin_elementwise_fma(daz, daz,
                     __builtin_elementwise_fma(day, day, dax * dax));
        v2f pb2 = __builtin_elementwise_fma(n2v, d1, pa2) + L2D(iABAB);
        v2f pc2 = __builtin_elementwise_fma(n2v, d2, pa2) + L2D(iACAC);

        v2f sub3 = __builtin_elementwise_fma(-(d1 * L2D(iIAB)), d1, pa2);
        v2f sub5 = __builtin_elementwise_fma(-(d2 * L2D(iIAC)), d2, pa2);
        v2f sub6 = __builtin_elementwise_fma(-(e63 * L2D(iIBC)), e63, pb2);
        v2f subI = (nd * L2D(iINN)) * nd;

        v2f mg = L2D(iMARG);
#undef L2D

        unsigned lo16, hi16;
        screen_face(d1.x, d2.x, d3.x, d4.x, d5.x, d6.x, va.x, vb.x, vc.x,
                    e63.x, e65.x, pa2.x, pb2.x, pc2.x,
                    sub3.x, sub5.x, sub6.x, subI.x, mg.x, ubmin, lo16);
        screen_face(d1.y, d2.y, d3.y, d4.y, d5.y, d6.y, va.y, vb.y, vc.y,
                    e63.y, e65.y, pa2.y, pb2.y, pc2.y,
                    sub3.y, sub5.y, sub6.y, subI.y, mg.y, ubmin, hi16);

        lbout[(fblk * (FPT / 2) + jp) * P_N + p] = lo16 | (hi16 << 16);
    }

    atomicMin(&minub[p], __float_as_uint(ubmin));
}

// =================== phase 2: exact eval of candidates ===================

__global__ __launch_bounds__(TPB) void k_exact(
    const float* __restrict__ points,
    const float* __restrict__ vertices,
    const int* __restrict__ faces,
    const unsigned* __restrict__ minub,
    const unsigned* __restrict__ lbin,
    unsigned long long* __restrict__ best)
{
    __shared__ float sf[FPT][21];

    const int pblk = blockIdx.x;
    const int fblk = blockIdx.y;
    const int t = threadIdx.x;

    if (t < FPT) {
        float fd[21];
        face_setup(vertices, faces, fblk * FPT + t, fd);
#pragma unroll
        for (int k = 0; k < 21; ++k) sf[t][k] = fd[k];
    }
    __syncthreads();

    const int p = pblk * TPB + t;
    const float px = points[3 * p + 0];
    const float py = points[3 * p + 1];
    const float pz = points[3 * p + 2];
    const float mub = __uint_as_float(minub[p]);

    unsigned long long bk = ~0ull;
    const int fbase = fblk * FPT;

    for (int jp = 0; jp < FPT / 2; ++jp) {
        unsigned w = lbin[(fblk * (FPT / 2) + jp) * P_N + p];
        float lo = __uint_as_float(w << 16);
        float hi = __uint_as_float(w & 0xFFFF0000u);
        if (lo <= mub) {
            float w1, w2, w3, dist;
            tri_eval_exact(px, py, pz, &sf[jp * 2][0], w1, w2, w3, dist);
            unsigned db = __float_as_uint(dist);
            if (dist != dist) db = 0u;
            unsigned long long key = ((unsigned long long)db << 32) | (unsigned)(fbase + jp * 2);
            bk = (key < bk) ? key : bk;
        }
        if (hi <= mub) {
            float w1, w2, w3, dist;
            tri_eval_exact(px, py, pz, &sf[jp * 2 + 1][0], w1, w2, w3, dist);
            unsigned db = __float_as_uint(dist);
            if (dist != dist) db = 0u;
            unsigned long long key = ((unsigned long long)db << 32) | (unsigned)(fbase + jp * 2 + 1);
            bk = (key < bk) ? key : bk;
        }
    }

    if (bk != ~0ull) atomicMin(&best[p], bk);
}

// =================== fallback full exact scan (R5, proven) ===================

__device__ __forceinline__ void region_w(
    float d1, float d2, float d3, float d4, float d5, float d6,
    float va, float vb, float vc, float e63, float e65, float denom,
    float& w1, float& w2, float& w3)
{
#pragma clang fp contract(off)
    bool m1 = (d1 <= 0.0f) & (d2 <= 0.0f);
    bool m2 = (d3 >= 0.0f) & (d4 <= d3);
    bool m3 = (vc <= 0.0f) & (d1 >= 0.0f) & (d3 <= 0.0f);
    bool m4 = (d6 >= 0.0f) & (d5 <= d6);
    bool m5 = (vb <= 0.0f) & (d2 >= 0.0f) & (d6 <= 0.0f);
    bool m6 = (va <= 0.0f) & (e63 >= 0.0f) & (e65 >= 0.0f);
    bool anym = m1 | m2 | m3 | m4 | m5 | m6;

    float n1  = m1 ? 0.0f : m2 ? 0.0f : m3 ? d1        : m4 ? 0.0f : m5 ? d2        : m6 ? e63       : vb;
    float ds1 = m1 ? 1.0f : m2 ? 1.0f : m3 ? (d1 - d3) : m4 ? 1.0f : m5 ? (d2 - d6) : m6 ? (e63 + e65) : denom;
    ds1 = (ds1 == 0.0f) ? 1.0f : ds1;
    float n2  = anym ? 0.0f : vc;
    float ds2 = anym ? 1.0f : ((denom == 0.0f) ? 1.0f : denom);

    float q1 = n1 / ds1;
    float q2 = n2 / ds2;
    float u = (1.0f - q1) - q2;

    w1 = m1 ? 1.0f : m2 ? 0.0f : m3 ? u    : m4 ? 0.0f : m5 ? u    : m6 ? 0.0f : u;
    w2 = m1 ? 0.0f : m2 ? 1.0f : m3 ? q1   : m4 ? 0.0f : m5 ? 0.0f : m6 ? u    : q1;
    w3 = m1 ? 0.0f : m2 ? 0.0f : m3 ? 0.0f : m4 ? 1.0f : m5 ? q1   : m6 ? q1   : q2;
}

__global__ __launch_bounds__(TPB) void k_scan_full(
    const float* __restrict__ points,
    const float* __restrict__ vertices,
    const int* __restrict__ faces,
    unsigned long long* __restrict__ best)
{
#pragma clang fp contract(off)
    __shared__ float sq[21][FPT];

    const int pblk = blockIdx.x;
    const int fblk = blockIdx.y;
    const int t = threadIdx.x;

    if (t < FPT) {
        int f = fblk * FPT + t;
        float fd[21];
        face_setup(vertices, faces, f, fd);
#pragma unroll
        for (int k = 0; k < 21; ++k) sq[k][t] = fd[k];
    }
    __syncthreads();

    const int p = pblk * TPB + t;
    const float px = points[3 * p + 0];
    const float py = points[3 * p + 1];
    const float pz = points[3 * p + 2];
    const v2f pxv = {px, px}, pyv = {py, py}, pzv = {pz, pz};

    unsigned int bestdb = 0xffffffffu;
    int bestf = 0;
    const int fbase = fblk * FPT;

#pragma unroll 2
    for (int j = 0; j < FPT; j += 2) {
#define LD2(q) (*(const v2f*)&sq[q][j])
        v2f axv = LD2(0),  ayv = LD2(1),  azv = LD2(2);
        v2f bxv = LD2(3),  byv = LD2(4),  bzv = LD2(5);
        v2f cxv = LD2(6),  cyv = LD2(7),  czv = LD2(8);
        v2f abxv = LD2(9),  abyv = LD2(10), abzv = LD2(11);
        v2f acxv = LD2(12), acyv = LD2(13), aczv = LD2(14);
        v2f daabv = LD2(15), daacv = LD2(16), dbabv = LD2(17);
        v2f dbacv = LD2(18), dcabv = LD2(19), dcacv = LD2(20);
#undef LD2

        v2f pab = __builtin_elementwise_fma(pzv, abzv,
                    __builtin_elementwise_fma(pyv, abyv, pxv * abxv));
        v2f pac = __builtin_elementwise_fma(pzv, aczv,
                    __builtin_elementwise_fma(pyv, acyv, pxv * acxv));

        v2f d1 = pab - daabv;
        v2f d2 = pac - daacv;
        v2f d3 = pab - dbabv;
        v2f d4 = pac - dbacv;
        v2f d5 = pab - dcabv;
        v2f d6 = pac - dcacv;

        v2f vcv = d1 * d4 - d3 * d2;
        v2f vbv = d5 * d2 - d1 * d6;
        v2f vav = d3 * d6 - d5 * d4;

        v2f e63 = d4 - d3;
        v2f e65 = d5 - d6;
        v2f denom = (vav + vbv) + vcv;

        float w1a, w2a, w3a, w1b, w2b, w3b;
        region_w(d1.x, d2.x, d3.x, d4.x, d5.x, d6.x,
                 vav.x, vbv.x, vcv.x, e63.x, e65.x, denom.x, w1a, w2a, w3a);
        region_w(d1.y, d2.y, d3.y, d4.y, d5.y, d6.y,
                 vav.y, vbv.y, vcv.y, e63.y, e65.y, denom.y, w1b, w2b, w3b);

        v2f w1v = {w1a, w1b};
        v2f w2v = {w2a, w2b};
        v2f w3v = {w3a, w3b};

        v2f cpx = (w1v * axv + w2v * bxv) + w3v * cxv;
        v2f cpy = (w1v * ayv + w2v * byv) + w3v * cyv;
        v2f cpz = (w1v * azv + w2v * bzv) + w3v * czv;
        v2f dx = pxv - cpx, dy = pyv - cpy, dz = pzv - cpz;
        v2f dist = (dx * dx + dy * dy) + dz * dz;

        float da = dist.x;
        float db = dist.y;
        unsigned int ua = __float_as_uint(da);
        unsigned int ub = __float_as_uint(db);
        if (da != da) ua = 0u;
        if (db != db) ub = 0u;
        if (ua < bestdb) { bestdb = ua; bestf = fbase + j; }
        if (ub < bestdb) { bestdb = ub; bestf = fbase + j + 1; }
    }

    unsigned long long key =
        ((unsigned long long)bestdb << 32) | (unsigned int)bestf;
    atomicMin(&best[p], key);
}

// =================== finalize ===================

__global__ __launch_bounds__(TPB) void k_final(
    const float* __restrict__ points,
    const float* __restrict__ vertices,
    const int* __restrict__ faces,
    const unsigned long long* __restrict__ best,
    float* __restrict__ out)
{
    const int p = blockIdx.x * TPB + threadIdx.x;
    if (p >= P_N) return;
    unsigned long long bk = best[p];
    int f = (int)(bk & 0xffffffffull);

    float fd[21];
    face_setup(vertices, faces, f, fd);

    const float px = points[3 * p + 0];
    const float py = points[3 * p + 1];
    const float pz = points[3 * p + 2];
    float w1, w2, w3, dist;
    tri_eval_exact(px, py, pz, fd, w1, w2, w3, dist);

    out[p] = (float)f;
    out[P_N + p] = w1;
    out[2 * P_N + p] = w2;
    out[3 * P_N + p] = w3;
}

extern "C" void kernel_launch(void* const* d_in, const int* in_sizes, int n_in,
                              void* d_out, int out_size, void* d_ws, size_t ws_size,
                              hipStream_t stream)
{
    const float* points = (const float*)d_in[0];
    const float* vertices = (const float*)d_in[1];
    const int* faces = (const int*)d_in[2];
    float* out = (float*)d_out;

    char* ws = (char*)d_ws;
    unsigned long long* best = (unsigned long long*)(ws + WS_BEST_OFF);

    hipMemsetAsync(best, 0xFF, P_N * sizeof(unsigned long long), stream);

    dim3 grid(P_N / TPB, NT);

    if (ws_size >= WS_NEEDED) {
        unsigned* minub = (unsigned*)(ws + WS_MINUB_OFF);
        unsigned* lbbuf = (unsigned*)(ws + WS_LB_OFF);
        // min_ub init to large float (0x7F7F7F7F = 3.39e38)
        hipMemsetAsync(minub, 0x7F, P_N * sizeof(unsigned), stream);
        k_screen<<<grid, TPB, 0, stream>>>(points, vertices, faces, minub, lbbuf);
        k_exact<<<grid, TPB, 0, stream>>>(points, vertices, faces, minub, lbbuf, best);
    } else {
        k_scan_full<<<grid, TPB, 0, stream>>>(points, vertices, faces, best);
    }

    k_final<<<(P_N + TPB - 1) / TPB, TPB, 0, stream>>>(points, vertices, faces, best, out);
}